// Round 1
// 1726.053 us; speedup vs baseline: 1.0732x; 1.0732x over previous
//
#include <hip/hip_runtime.h>
#include <hip/hip_bf16.h>
#include <cstdint>

typedef __hip_bfloat16 bf16;
typedef unsigned short u16;
typedef unsigned int u32;
typedef __attribute__((ext_vector_type(8))) short short8;
typedef __attribute__((ext_vector_type(4))) float f32x4;

__device__ __forceinline__ float tofloat(float x){ return x; }
__device__ __forceinline__ float tofloat(bf16 x){ return __bfloat162float(x); }
__device__ __forceinline__ float b2f(u16 a){ return __uint_as_float(((unsigned)a) << 16); }
__device__ __forceinline__ u16 f2b(float f){           // round-to-nearest-even
    unsigned u = __float_as_uint(f);
    return (u16)((u + 0x7FFFu + ((u >> 16) & 1u)) >> 16);
}
__device__ __forceinline__ void storec(float* p, float v){ *p = v; }
__device__ __forceinline__ void storec(u16* p, float v){ *p = f2b(v); }

static inline int divup(long a, long b){ return (int)((a + b - 1) / b); }

// ---------------- input dtype detection -------------------------------------
__global__ void zero_int(int* p){ *p = 0; }

__global__ void detect_f32(const u16* __restrict__ h, long n, int* flag)
{
    long i = (long)blockIdx.x * blockDim.x + threadIdx.x;
    long st = (long)gridDim.x * blockDim.x;
    int c = 0;
    for (; i < n; i += st)
        if (((h[i] >> 7) & 0xFF) == 0xFF) c++;
    if (c) atomicAdd(flag, c);
}

// convert all weights: fp32 pool + bf16 pool in one launch
struct ConvTab { const void* src[14]; float* dst[14]; u16* dstB[14]; int n[14]; };

__global__ void conv_all(ConvTab t, const int* __restrict__ flagp)
{
    bool f32 = (*flagp != 0);
    int seg = blockIdx.y;
    const void* s = t.src[seg];
    float* d = t.dst[seg];
    u16*   dB = t.dstB[seg];
    int n = t.n[seg];
    long i = (long)blockIdx.x * blockDim.x + threadIdx.x;
    long st = (long)gridDim.x * blockDim.x;
    for (; i < n; i += st) {
        float v = f32 ? ((const float*)s)[i] : tofloat(((const bf16*)s)[i]);
        d[i] = v; dB[i] = f2b(v);
    }
}

__global__ void conv_in(const void* __restrict__ src, float* __restrict__ dst,
                        long n, const int* __restrict__ flagp)
{
    bool f32 = (*flagp != 0);
    long i = (long)blockIdx.x * blockDim.x + threadIdx.x;
    long st = (long)gridDim.x * blockDim.x;
    for (; i < n; i += st)
        dst[i] = f32 ? ((const float*)src)[i] : tofloat(((const bf16*)src)[i]);
}

__global__ void conv_dual_b16(const void* __restrict__ src, u16* __restrict__ dst,
                              long n, const int* __restrict__ flagp)
{
    bool f32 = (*flagp != 0);
    long i = (long)blockIdx.x * blockDim.x + threadIdx.x;
    long st = (long)gridDim.x * blockDim.x;
    for (; i < n; i += st)
        dst[i] = f32 ? f2b(((const float*)src)[i]) : ((const u16*)src)[i];
}

__global__ void conv_f32_b16(const float* __restrict__ src, u16* __restrict__ dst, long n)
{
    long i = (long)blockIdx.x * blockDim.x + threadIdx.x;
    long st = (long)gridDim.x * blockDim.x;
    for (; i < n; i += st) dst[i] = f2b(src[i]);
}

// convert mol_x fp32 -> bf16 copy (only when input is fp32); vectorized x4
__global__ void conv_molx(const float* __restrict__ src, u16* __restrict__ dst,
                          long n4, const int* __restrict__ flagp)
{
    if (*flagp == 0) return;   // input already bf16; agg reads original
    long i = (long)blockIdx.x * blockDim.x + threadIdx.x;
    long st = (long)gridDim.x * blockDim.x;
    for (; i < n4; i += st) {
        float4 v = ((const float4*)src)[i];
        ushort4 o;
        o.x = f2b(v.x); o.y = f2b(v.y); o.z = f2b(v.z); o.w = f2b(v.w);
        ((ushort4*)dst)[i] = o;
    }
}

// ---------------- CSR edge flattening ---------------------------------------
// ebM[j] = {src[bins[j]], bits(en[bins[j]])} -- removes double indirection
__global__ void flatten_mol(const int* __restrict__ bins, const int* __restrict__ src,
                            const float* __restrict__ en, long E, int2* __restrict__ out)
{
    long i = (long)blockIdx.x * blockDim.x + threadIdx.x;
    long st = (long)gridDim.x * blockDim.x;
    for (; i < E; i += st) {
        int e = bins[i];
        out[i] = make_int2(src[e], __float_as_int(en[e]));
    }
}

// ebK[j] = {et*NKG+src (row index into HR), bits(en)}
__global__ void flatten_kg(const int* __restrict__ bins, const int* __restrict__ src,
                           const int* __restrict__ et, const float* __restrict__ en,
                           long E, int NKG, int2* __restrict__ out)
{
    long i = (long)blockIdx.x * blockDim.x + threadIdx.x;
    long st = (long)gridDim.x * blockDim.x;
    for (; i < E; i += st) {
        int e = bins[i];
        out[i] = make_int2(et[e] * NKG + src[e], __float_as_int(en[e]));
    }
}

// ---------------- MFMA GEMM: C[M,N] = A[M,K] @ B[K,N], bf16 in, fp32 acc ----
// 64x64 tile, 256 thr = 4 waves (2x2), BK=32 (one mfma K). N%64==0, K%32==0.
template<typename TC>
__global__ __launch_bounds__(256)
void gemm_mfma(const u16* __restrict__ A, int lda,
               const u16* __restrict__ B, int ldb,
               TC* __restrict__ C, int ldc,
               int M, int N, int K, long sB, long sC)
{
    __shared__ __align__(16) u16 As[64][40];   // [m][k], stride 80 B
    __shared__ __align__(16) u16 Bs[64][40];   // [n][k] (transposed)
    const u16* Bp = B + (long)blockIdx.z * sB;
    TC*        Cp = C + (long)blockIdx.z * sC;
    const int tid = threadIdx.x;
    const int lane = tid & 63, wave = tid >> 6;
    const int l15 = lane & 15, quad = lane >> 4;
    const int wm = (wave & 1) * 32, wn = (wave >> 1) * 32;
    const int row0 = blockIdx.x * 64, col0 = blockIdx.y * 64;
    const int arow = tid >> 2, ak = (tid & 3) * 8;
    const int bk = tid >> 3,  bn = (tid & 7) * 8;

    f32x4 acc[2][2];
#pragma unroll
    for (int i = 0; i < 2; i++)
#pragma unroll
        for (int j = 0; j < 2; j++)
#pragma unroll
            for (int r = 0; r < 4; r++) acc[i][j][r] = 0.f;

    for (int k0 = 0; k0 < K; k0 += 32) {
        {   // stage A: 64 rows x 32 k
            int r = row0 + arow;
            ushort4 v0 = {0,0,0,0}, v1 = {0,0,0,0};
            if (r < M) {
                const u16* p = A + (long)r * lda + k0 + ak;
                v0 = *(const ushort4*)p;
                v1 = *(const ushort4*)(p + 4);
            }
            *(ushort4*)&As[arow][ak]     = v0;
            *(ushort4*)&As[arow][ak + 4] = v1;
        }
        {   // stage B transposed: Bs[n][k]
            const u16* p = Bp + (long)(k0 + bk) * ldb + col0 + bn;
            ushort4 v0 = *(const ushort4*)p;
            ushort4 v1 = *(const ushort4*)(p + 4);
            Bs[bn + 0][bk] = v0.x; Bs[bn + 1][bk] = v0.y;
            Bs[bn + 2][bk] = v0.z; Bs[bn + 3][bk] = v0.w;
            Bs[bn + 4][bk] = v1.x; Bs[bn + 5][bk] = v1.y;
            Bs[bn + 6][bk] = v1.z; Bs[bn + 7][bk] = v1.w;
        }
        __syncthreads();
        short8 a0 = *(const short8*)&As[wm + l15][quad * 8];
        short8 a1 = *(const short8*)&As[wm + 16 + l15][quad * 8];
        short8 b0 = *(const short8*)&Bs[wn + l15][quad * 8];
        short8 b1 = *(const short8*)&Bs[wn + 16 + l15][quad * 8];
        acc[0][0] = __builtin_amdgcn_mfma_f32_16x16x32_bf16(a0, b0, acc[0][0], 0, 0, 0);
        acc[0][1] = __builtin_amdgcn_mfma_f32_16x16x32_bf16(a0, b1, acc[0][1], 0, 0, 0);
        acc[1][0] = __builtin_amdgcn_mfma_f32_16x16x32_bf16(a1, b0, acc[1][0], 0, 0, 0);
        acc[1][1] = __builtin_amdgcn_mfma_f32_16x16x32_bf16(a1, b1, acc[1][1], 0, 0, 0);
        __syncthreads();
    }
#pragma unroll
    for (int i = 0; i < 2; i++)
#pragma unroll
        for (int j = 0; j < 2; j++)
#pragma unroll
            for (int r = 0; r < 4; r++) {
                int row = row0 + wm + i * 16 + quad * 4 + r;
                int col = col0 + wn + j * 16 + l15;
                if (row < M) storec(&Cp[(long)row * ldc + col], acc[i][j][r]);
            }
}

// ---------------- vector GEMM (fp32, small) ---------------------------------
__global__ __launch_bounds__(256)
void gemm64(const float* __restrict__ A, int lda,
            const float* __restrict__ B, int ldb,
            float* __restrict__ C, int ldc,
            int M, int N, int K)
{
    __shared__ float As[16][68];
    __shared__ float Bs[16][68];
    const int tid = threadIdx.x;
    const int row0 = blockIdx.x * 64, col0 = blockIdx.y * 64;
    float acc[4][4];
#pragma unroll
    for (int i = 0; i < 4; i++)
#pragma unroll
        for (int j = 0; j < 4; j++) acc[i][j] = 0.f;
    const int ar = tid >> 2, ak = (tid & 3) * 4;
    const int bk = tid >> 4, bc = (tid & 15) * 4;
    const int ty4 = (tid >> 4) * 4, tx4 = (tid & 15) * 4;
    for (int k0 = 0; k0 < K; k0 += 16) {
        {
            int row = row0 + ar;
            float4 v = make_float4(0.f, 0.f, 0.f, 0.f);
            if (row < M) v = *(const float4*)(A + (long)row * lda + k0 + ak);
            As[ak + 0][ar] = v.x; As[ak + 1][ar] = v.y;
            As[ak + 2][ar] = v.z; As[ak + 3][ar] = v.w;
        }
        {
            int c = col0 + bc;
            float4 v = make_float4(0.f, 0.f, 0.f, 0.f);
            if (c < N) v = *(const float4*)(B + (long)(k0 + bk) * ldb + c);
            *(float4*)&Bs[bk][bc] = v;
        }
        __syncthreads();
#pragma unroll
        for (int k = 0; k < 16; k++) {
            float4 a = *(const float4*)&As[k][ty4];
            float4 b = *(const float4*)&Bs[k][tx4];
            acc[0][0] += a.x * b.x; acc[0][1] += a.x * b.y; acc[0][2] += a.x * b.z; acc[0][3] += a.x * b.w;
            acc[1][0] += a.y * b.x; acc[1][1] += a.y * b.y; acc[1][2] += a.y * b.z; acc[1][3] += a.y * b.w;
            acc[2][0] += a.z * b.x; acc[2][1] += a.z * b.y; acc[2][2] += a.z * b.z; acc[2][3] += a.z * b.w;
            acc[3][0] += a.w * b.x; acc[3][1] += a.w * b.y; acc[3][2] += a.w * b.z; acc[3][3] += a.w * b.w;
        }
        __syncthreads();
    }
    int c = col0 + tx4;
#pragma unroll
    for (int i = 0; i < 4; i++) {
        int r = row0 + ty4 + i;
        if (r < M && c < N)
            *(float4*)&C[(long)r * ldc + c] =
                make_float4(acc[i][0], acc[i][1], acc[i][2], acc[i][3]);
    }
}

// ---------------- utility / CSR build ---------------------------------------
__global__ void filli(int* p, long n, int v)
{
    long i = (long)blockIdx.x * blockDim.x + threadIdx.x;
    long st = (long)gridDim.x * blockDim.x;
    for (; i < n; i += st) p[i] = v;
}

__global__ void hist_int(const int* __restrict__ key, long n, int* __restrict__ h)
{
    long i = (long)blockIdx.x * blockDim.x + threadIdx.x;
    long st = (long)gridDim.x * blockDim.x;
    for (; i < n; i += st) atomicAdd(&h[key[i]], 1);
}

__global__ __launch_bounds__(1024)
void scan_bsum(const int* __restrict__ in, int n, int* __restrict__ btot)
{
    __shared__ int sh[1024];
    int tid = threadIdx.x;
    int i0 = blockIdx.x * 4096 + tid * 4;
    int s = 0;
#pragma unroll
    for (int t = 0; t < 4; t++) { int idx = i0 + t; s += (idx < n) ? in[idx] : 0; }
    sh[tid] = s;
    __syncthreads();
    for (int off = 512; off > 0; off >>= 1) {
        if (tid < off) sh[tid] += sh[tid + off];
        __syncthreads();
    }
    if (tid == 0) btot[blockIdx.x] = sh[0];
}

__global__ void scan_tiny(const int* __restrict__ btot, int nb, int* __restrict__ boff)
{
    if (threadIdx.x == 0) {
        int c = 0;
        for (int b = 0; b < nb; b++) { boff[b] = c; c += btot[b]; }
        boff[nb] = c;
    }
}

__global__ __launch_bounds__(1024)
void scan_final(const int* __restrict__ in, int n, const int* __restrict__ boff,
                int nb, int* __restrict__ out)
{
    __shared__ int buf[1024];
    int tid = threadIdx.x;
    int i0 = blockIdx.x * 4096 + tid * 4;
    int v[4]; int s = 0;
#pragma unroll
    for (int t = 0; t < 4; t++) {
        int idx = i0 + t;
        v[t] = (idx < n) ? in[idx] : 0;
        s += v[t];
    }
    buf[tid] = s;
    __syncthreads();
    for (int off = 1; off < 1024; off <<= 1) {
        int t = (tid >= off) ? buf[tid - off] : 0;
        __syncthreads();
        buf[tid] += t;
        __syncthreads();
    }
    int excl = buf[tid] - s + boff[blockIdx.x];
#pragma unroll
    for (int t = 0; t < 4; t++) {
        int idx = i0 + t;
        if (idx < n) out[idx] = excl;
        excl += v[t];
    }
    if (blockIdx.x == 0 && tid == 0) out[n] = boff[nb];
}

__global__ void bin_by(const int* __restrict__ key, long n,
                       const int* __restrict__ off, int* __restrict__ cursor,
                       int* __restrict__ bins)
{
    long i = (long)blockIdx.x * blockDim.x + threadIdx.x;
    long st = (long)gridDim.x * blockDim.x;
    for (; i < n; i += st) {
        int k = key[i];
        int pos = off[k] + atomicAdd(&cursor[k], 1);
        bins[pos] = (int)i;
    }
}

__global__ void dinv_from_deg(const int* __restrict__ deg, float* __restrict__ dinv, long n)
{
    long i = (long)blockIdx.x * blockDim.x + threadIdx.x;
    long st = (long)gridDim.x * blockDim.x;
    for (; i < n; i += st) dinv[i] = rsqrtf((float)(deg[i] + 1));
}

__global__ void kg_cnt(const int* __restrict__ dst, const int* __restrict__ et,
                       long E, int NKG, float* cnt)
{
    long i = (long)blockIdx.x * blockDim.x + threadIdx.x;
    long st = (long)gridDim.x * blockDim.x;
    for (; i < E; i += st) atomicAdd(&cnt[(long)et[i] * NKG + dst[i]], 1.0f);
}

__global__ void kg_enorm(const int* __restrict__ dst, const int* __restrict__ et,
                         const float* __restrict__ cnt, long E, int NKG,
                         float* __restrict__ en)
{
    long i = (long)blockIdx.x * blockDim.x + threadIdx.x;
    long st = (long)gridDim.x * blockDim.x;
    for (; i < E; i += st)
        en[i] = 1.0f / fmaxf(cnt[(long)et[i] * NKG + dst[i]], 1.0f);
}

__global__ void mol_enorm(const int* __restrict__ src, const int* __restrict__ dst,
                          const float* __restrict__ dinv, long E, float* __restrict__ en)
{
    long i = (long)blockIdx.x * blockDim.x + threadIdx.x;
    long st = (long)gridDim.x * blockDim.x;
    for (; i < E; i += st) en[i] = dinv[src[i]] * dinv[dst[i]];
}

// ---------------- batch-norm stats ------------------------------------------
__global__ __launch_bounds__(512)
void colstats_part(const float* __restrict__ X, int M, int N, int lgN, int G,
                   float* __restrict__ p1, float* __restrict__ p2)
{
    __shared__ float sh1[512], sh2[512];
    int tid = threadIdx.x;
    int col = tid & (N - 1);
    int grp = tid >> lgN;
    float s1 = 0.f, s2 = 0.f;
    for (long row = (long)blockIdx.x * G + grp; row < M; row += (long)gridDim.x * G) {
        float v = X[row * N + col];
        s1 += v; s2 += v * v;
    }
    sh1[tid] = s1; sh2[tid] = s2;
    __syncthreads();
    if (grp == 0) {
        for (int g = 1; g < G; g++) { s1 += sh1[col + (g << lgN)]; s2 += sh2[col + (g << lgN)]; }
        p1[blockIdx.x * N + col] = s1;
        p2[blockIdx.x * N + col] = s2;
    }
}

__global__ __launch_bounds__(512)
void colstats_part_b16(const u16* __restrict__ X, int M, int ld, int c0,
                       float* __restrict__ p1, float* __restrict__ p2)
{
    __shared__ float sh1[512], sh2[512];
    int tid = threadIdx.x;
    int col = tid & 63;
    int grp = tid >> 6;
    float s1 = 0.f, s2 = 0.f;
    for (long row = (long)blockIdx.x * 8 + grp; row < M; row += (long)gridDim.x * 8) {
        float v = b2f(X[row * ld + c0 + col]);
        s1 += v; s2 += v * v;
    }
    sh1[tid] = s1; sh2[tid] = s2;
    __syncthreads();
    if (grp == 0) {
        for (int g = 1; g < 8; g++) { s1 += sh1[col + (g << 6)]; s2 += sh2[col + (g << 6)]; }
        p1[blockIdx.x * 64 + col] = s1;
        p2[blockIdx.x * 64 + col] = s2;
    }
}

__global__ void colstats_reduce(const float* __restrict__ p1, const float* __restrict__ p2,
                                int nblk, int N, float invM,
                                float* __restrict__ s1o, float* __restrict__ s2o)
{
    int j = threadIdx.x;
    if (j >= N) return;
    float a = 0.f, c = 0.f;
    for (int b = 0; b < nblk; b += 4) {
        a += p1[(b + 0) * N + j] + p1[(b + 1) * N + j] + p1[(b + 2) * N + j] + p1[(b + 3) * N + j];
        c += p2[(b + 0) * N + j] + p2[(b + 1) * N + j] + p2[(b + 2) * N + j] + p2[(b + 3) * N + j];
    }
    float mean = a * invM;
    float var  = fmaxf(c * invM - mean * mean, 0.f);
    s1o[j] = mean;
    s2o[j] = rsqrtf(var + 1e-5f);
}

__global__ void bn_apply(float* X, long total, int mask,
                         const float* __restrict__ s1, const float* __restrict__ s2)
{
    long i = (long)blockIdx.x * blockDim.x + threadIdx.x;
    long st = (long)gridDim.x * blockDim.x;
    for (; i < total; i += st) {
        int j = (int)(i & mask);
        X[i] = fmaxf((X[i] - s1[j]) * s2[j], 0.f);
    }
}

// BN+ReLU, fp32 in place AND bf16 copy
__global__ void bn_apply_dual(float* __restrict__ X, u16* __restrict__ Xb, long total,
                              int mask, const float* __restrict__ s1,
                              const float* __restrict__ s2)
{
    long i = (long)blockIdx.x * blockDim.x + threadIdx.x;
    long st = (long)gridDim.x * blockDim.x;
    for (; i < total; i += st) {
        int j = (int)(i & mask);
        float y = fmaxf((X[i] - s1[j]) * s2[j], 0.f);
        X[i] = y;
        Xb[i] = f2b(y);
    }
}

// BN+ReLU in place on bf16 strided chunk [M,64] at X[n*ld + c0 + f]
__global__ void bn_apply_b16(u16* __restrict__ X, long total, int ld, int c0,
                             const float* __restrict__ s1, const float* __restrict__ s2)
{
    long i = (long)blockIdx.x * blockDim.x + threadIdx.x;
    long st = (long)gridDim.x * blockDim.x;
    for (; i < total; i += st) {
        long n = i >> 6;
        int  f = (int)(i & 63);
        u16* p = X + n * ld + c0 + f;
        *p = f2b(fmaxf((b2f(*p) - s1[f]) * s2[f], 0.f));
    }
}

// ---------------- CSR aggregation (no atomics) ------------------------------
// aggregate bf16 [NM,64] -> bf16 out; eb[j] = {src, en_bits} (flattened CSR)
__global__ __launch_bounds__(256)
void mol_agg_in(const void* __restrict__ Xraw, const u16* __restrict__ Xcvt,
                const int* __restrict__ flagp, const float* __restrict__ dinv,
                const int* __restrict__ off, const int2* __restrict__ eb,
                int NM, u16* __restrict__ out)
{
    const u16* X = (*flagp != 0) ? Xcvt : (const u16*)Xraw;
    int wid  = (int)(((long)blockIdx.x * 256 + threadIdx.x) >> 6);
    int lane = threadIdx.x & 63;
    if (wid >= NM) return;
    float dv = dinv[wid];
    float acc = b2f(X[(long)wid * 64 + lane]) * dv * dv;
    int j = off[wid], j1 = off[wid + 1];
    for (; j + 1 < j1; j += 2) {
        int2 e0 = eb[j], e1 = eb[j + 1];
        float v0 = b2f(X[(long)e0.x * 64 + lane]);
        float v1 = b2f(X[(long)e1.x * 64 + lane]);
        acc += v0 * __int_as_float(e0.y) + v1 * __int_as_float(e1.y);
    }
    if (j < j1) {
        int2 e = eb[j];
        acc += b2f(X[(long)e.x * 64 + lane]) * __int_as_float(e.y);
    }
    out[(long)wid * 64 + lane] = f2b(acc);
}

// aggregate bf16 [NM,128] -> bf16 [NM,128]; lane covers cols 2l,2l+1
__global__ __launch_bounds__(256)
void mol_agg128(const u16* __restrict__ G, const float* __restrict__ dinv,
                const int* __restrict__ off, const int2* __restrict__ eb,
                int NM, u16* __restrict__ out)
{
    int wid  = (int)(((long)blockIdx.x * 256 + threadIdx.x) >> 6);
    int lane = threadIdx.x & 63;
    if (wid >= NM) return;
    float dv = dinv[wid], dv2 = dv * dv;
    u32 u = *(const u32*)(G + (long)wid * 128 + 2 * lane);
    float a0 = b2f((u16)(u & 0xFFFF)) * dv2;
    float a1 = b2f((u16)(u >> 16)) * dv2;
    int j = off[wid], j1 = off[wid + 1];
    for (; j + 1 < j1; j += 2) {
        int2 e0 = eb[j], e1 = eb[j + 1];
        u32 v0 = *(const u32*)(G + (long)e0.x * 128 + 2 * lane);
        u32 v1 = *(const u32*)(G + (long)e1.x * 128 + 2 * lane);
        float n0 = __int_as_float(e0.y), n1 = __int_as_float(e1.y);
        a0 += b2f((u16)(v0 & 0xFFFF)) * n0 + b2f((u16)(v1 & 0xFFFF)) * n1;
        a1 += b2f((u16)(v0 >> 16)) * n0 + b2f((u16)(v1 >> 16)) * n1;
    }
    if (j < j1) {
        int2 e = eb[j];
        u32 v = *(const u32*)(G + (long)e.x * 128 + 2 * lane);
        float n = __int_as_float(e.y);
        a0 += b2f((u16)(v & 0xFFFF)) * n;
        a1 += b2f((u16)(v >> 16)) * n;
    }
    u32 o = (u32)f2b(a0) | ((u32)f2b(a1) << 16);
    *(u32*)(out + (long)wid * 128 + 2 * lane) = o;
}

// RGCN gather: hr bf16 [8,NKG,128]; eb[j] = {r*NKG+src, en_bits}
__global__ __launch_bounds__(256)
void rgcn_agg128(const u16* __restrict__ hr, const int* __restrict__ off,
                 const int2* __restrict__ eb,
                 int NKG, float* __restrict__ out, int ldout, int c0)
{
    int wid  = (int)(((long)blockIdx.x * 256 + threadIdx.x) >> 6);
    int lane = threadIdx.x & 63;
    if (wid >= NKG) return;
    float a0 = 0.f, a1 = 0.f;
    int j = off[wid], j1 = off[wid + 1];
    for (; j + 1 < j1; j += 2) {
        int2 e0 = eb[j], e1 = eb[j + 1];
        u32 u0 = *(const u32*)(hr + (long)e0.x * 128 + 2 * lane);
        u32 u1 = *(const u32*)(hr + (long)e1.x * 128 + 2 * lane);
        float n0 = __int_as_float(e0.y), n1 = __int_as_float(e1.y);
        a0 += b2f((u16)(u0 & 0xFFFF)) * n0 + b2f((u16)(u1 & 0xFFFF)) * n1;
        a1 += b2f((u16)(u0 >> 16)) * n0 + b2f((u16)(u1 >> 16)) * n1;
    }
    if (j < j1) {
        int2 e = eb[j];
        u32 u0 = *(const u32*)(hr + (long)e.x * 128 + 2 * lane);
        float n0 = __int_as_float(e.y);
        a0 += b2f((u16)(u0 & 0xFFFF)) * n0;
        a1 += b2f((u16)(u0 >> 16)) * n0;
    }
    float2* o = (float2*)(out + (long)wid * ldout + c0 + 2 * lane);
    float2 v = *o; v.x += a0; v.y += a1; *o = v;
}

// mean-pool bf16 chunk [NM,64] with fused BN+ReLU
__global__ __launch_bounds__(256)
void pool_b16(const u16* __restrict__ g, const int* __restrict__ off,
              const int* __restrict__ bins, int ND,
              const float* __restrict__ s1, const float* __restrict__ s2,
              float* __restrict__ gout, int c0)
{
    int wid  = (int)(((long)blockIdx.x * 256 + threadIdx.x) >> 6);
    int lane = threadIdx.x & 63;
    if (wid >= ND) return;
    float m = s1[lane], r = s2[lane];
    int j0 = off[wid], j1 = off[wid + 1];
    float acc = 0.f;
    for (int j = j0; j < j1; j++)
        acc += fmaxf((b2f(g[(long)bins[j] * 64 + lane]) - m) * r, 0.f);
    gout[(long)wid * 256 + c0 + lane] = acc / fmaxf((float)(j1 - j0), 1.0f);
}

// ---------------- attention fusion ------------------------------------------
__global__ void attention_fuse(const float* __restrict__ go, const float* __restrict__ fpv,
                               const float* __restrict__ W1, const float* __restrict__ B1,
                               const float* __restrict__ W2,
                               float* __restrict__ emb, float* __restrict__ beta_out)
{
    int d = blockIdx.x;
    int t = threadIdx.x;
    __shared__ float z[2][256];
    __shared__ float red[128];
    for (int c = t; c < 256; c += 128) {
        z[0][c] = go[(long)d * 256 + c];
        z[1][c] = fpv[(long)d * 256 + c];
    }
    __syncthreads();
    float s[2];
    for (int v = 0; v < 2; v++) {
        float acc = B1[t];
        for (int k = 0; k < 256; k++) acc += z[v][k] * W1[k * 128 + t];
        red[t] = tanhf(acc) * W2[t];
        __syncthreads();
        for (int off = 64; off > 0; off >>= 1) {
            if (t < off) red[t] += red[t + off];
            __syncthreads();
        }
        s[v] = red[0];
        __syncthreads();
    }
    float m = fmaxf(s[0], s[1]);
    float e0 = expf(s[0] - m), e1 = expf(s[1] - m);
    float inv = 1.0f / (e0 + e1);
    float b0 = e0 * inv, b1 = e1 * inv;
    for (int c = t; c < 256; c += 128)
        emb[(long)d * 256 + c] = b0 * z[0][c] + b1 * z[1][c];
    if (t == 0) {
        beta_out[d * 2 + 0] = b0;
        beta_out[d * 2 + 1] = b1;
    }
}

// ---------------- final linear + log_softmax, fused BN on x4 ----------------
__global__ void logits_out_bn(const float* __restrict__ x4,
                              const float* __restrict__ s1, const float* __restrict__ s2,
                              const float* __restrict__ w, const float* __restrict__ b,
                              float* __restrict__ out, int NKG)
{
    int i = blockIdx.x * blockDim.x + threadIdx.x;
    if (i >= NKG) return;
    float a0 = b[0], a1 = b[1];
    for (int k = 0; k < 64; k++) {
        float v = fmaxf((x4[(long)i * 64 + k] - s1[k]) * s2[k], 0.f);
        a0 += v * w[k * 2 + 0];
        a1 += v * w[k * 2 + 1];
    }
    float m = fmaxf(a0, a1);
    float lse = m + logf(expf(a0 - m) + expf(a1 - m));
    out[i * 2 + 0] = a0 - lse;
    out[i * 2 + 1] = a1 - lse;
}

// ============================================================================
extern "C" void kernel_launch(void* const* d_in, const int* in_sizes, int n_in,
                              void* d_out, int out_size, void* d_ws, size_t ws_size,
                              hipStream_t stream)
{
    (void)in_sizes; (void)n_in; (void)out_size; (void)ws_size;
    const int ND = 4096, NM = 131072, NKG = 9510, NGENE = 5414;
    const long EM = 524288, EK = 524288;

    const void* fp_data = d_in[0];
    const void* mol_x   = d_in[1];
    const int*  mol_batch = (const int*)d_in[2];
    const int*  mol_ei  = (const int*)d_in[3];
    const int*  kg_ei   = (const int*)d_in[4];
    const int*  kg_et   = (const int*)d_in[5];

    const int* mol_src = mol_ei;
    const int* mol_dst = mol_ei + EM;
    const int* kg_src  = kg_ei;
    const int* kg_dst  = kg_ei + EK;

    float* out_ls   = (float*)d_out;          // [9510,2] fp32
    float* out_beta = (float*)d_out + 19020;  // [4096,2,1] fp32

    // ---- workspace carve (~117 MB) ----
    char* wp = (char*)d_ws;
    auto carve = [&](size_t bytes) { char* p = wp; wp += (bytes + 255) & ~(size_t)255; return p; };
    float* stats = (float*)carve(4096);
    int*   flag  = (int*)carve(256);
    float* dinv  = (float*)carve((size_t)NM * 4);
    float* enM   = (float*)carve((size_t)EM * 4);
    float* enK   = (float*)carve((size_t)EK * 4);
    float* part1 = (float*)carve((size_t)64 * 512 * 4);
    float* part2 = (float*)carve((size_t)64 * 512 * 4);
    int*   sbt   = (int*)carve(256);
    int*   sbo   = (int*)carve(256);
    float* Wpool = (float*)carve((size_t)1630000 * 4);     // fp32 weights
    u16*   WpoolB= (u16*)carve((size_t)1630000 * 2);       // bf16 weights
    float* fpb   = (float*)carve((size_t)ND * 256 * 4);
    float* gout  = (float*)carve((size_t)ND * 256 * 4);
    // zero-span
    char*  z0    = wp;
    float* cntK  = (float*)carve((size_t)8 * NKG * 4);
    int* mdeg = (int*)carve((size_t)NM * 4);
    int* mcur = (int*)carve((size_t)NM * 4);
    int* kdeg = (int*)carve((size_t)NKG * 4);
    int* kcur = (int*)carve((size_t)NKG * 4);
    int* pdeg = (int*)carve((size_t)ND * 4);
    int* pcur = (int*)carve((size_t)ND * 4);
    char*  z1    = wp;
    int* moff = (int*)carve((size_t)(NM + 1) * 4);
    int* mbins= (int*)carve((size_t)EM * 4);
    int* koff = (int*)carve((size_t)(NKG + 1) * 4);
    int* kbins= (int*)carve((size_t)EK * 4);
    int* poff = (int*)carve((size_t)(ND + 1) * 4);
    int* pbins= (int*)carve((size_t)NM * 4);
    char*  REG1  = carve((size_t)NM * 128 * 2);            // 33.6 MB
    char*  REG2  = carve((size_t)NM * 128 * 2);            // 33.6 MB
    u16*   HB    = (u16*)carve((size_t)NM * 64 * 2);       // 16.8 MB

    // phase views
    float* fp1 = (float*)REG1;                 // fp: [4096,512] f32
    u16*   XB  = (u16*)REG1;                   // mol pre: [NM,64] bf16 converted input
    u16*   G1  = (u16*)REG1;                   // mol: [NM,128] bf16
    float* xkg = (float*)REG1;                 // rgcn: x chain f32
    float* x2  = xkg + (size_t)NKG * 256;
    float* x3  = x2  + (size_t)NKG * 256;
    float* x4  = x3  + (size_t)NKG * 128;
    u16*   Xfb = (u16*)REG2;                   // fp: [4096,1024] bf16
    u16*   G1A = (u16*)REG2;                   // mol: [NM,128] bf16 aggregated
    u16*   HR  = (u16*)REG2;                   // rgcn: [8,NKG,128] bf16
    u16*   xb  = HR + (size_t)8 * NKG * 128;   // [NKG,256] bf16
    u16*   x2b = xb + (size_t)NKG * 256;       // [NKG,256] bf16
    u16*   fp1b = HB;                          // fp: [4096,512] bf16
    u16*   Xagg = HB;                          // mol L1: [NM,64] bf16
    // flattened CSR edge tables (aliased; lifetimes verified):
    //   ebM lives in gout (gout first written by pool_b16, after mol_agg128 retires)
    //   ebK lives in fpb (fpb dead after attention_fuse; ebK used by rgcn_agg only)
    int2* ebM = (int2*)gout;                   // EM*8 == ND*256*4 bytes exactly
    int2* ebK = (int2*)fpb;                    // EK*8 == ND*256*4 bytes exactly

    // ---- dtype detect + weight conversion (fp32 + bf16 pools) ----
    zero_int<<<1, 1, 0, stream>>>(flag);
    detect_f32<<<1024, 256, 0, stream>>>((const u16*)fp_data, (long)ND * 1024, flag);
    ConvTab tab;
    const int widx[14] = {6, 8, 10, 12, 14, 15, 16, 18, 19, 21, 22, 24, 26, 27};
    const int wn[14]   = {1024*512, 512*256, 64*128, 128*256, 256*128, 128, 128,
                          8*256*256, 256*256, 8*256*128, 256*128, 128*64, 64*2, 2};
    float* wf[14]; u16* wb[14];
    {
        size_t o = 0;
        for (int i = 0; i < 14; i++) {
            tab.src[i]  = d_in[widx[i]];
            tab.dst[i]  = Wpool + o;
            tab.dstB[i] = WpoolB + o;
            tab.n[i]    = wn[i];
            wf[i] = Wpool + o; wb[i] = WpoolB + o;
            o += (size_t)wn[i];
        }
    }
    conv_all<<<dim3(32, 14), 256, 0, stream>>>(tab, flag);
    u16 *fp_w1b = wb[0], *fp_w2b = wb[1], *gcn_w1b = wb[2], *gcn_w2b = wb[3];
    float *att_w1c = wf[4], *att_b1c = wf[5], *att_w2c = wf[6];
    u16 *rg_w1b = wb[7], *rg_root1b = wb[8], *rg_w2b = wb[9], *rg_root2b = wb[10];
    float *lin1_wc = wf[11], *lin2_wc = wf[12], *lin2_bc = wf[13];

    // ---- CSR builds ----
    filli<<<512, 256, 0, stream>>>((int*)z0, (long)(z1 - z0) / 4, 0);
    auto scan = [&](const int* deg, int* off, int n) {
        int nb = divup(n, 4096);
        scan_bsum<<<nb, 1024, 0, stream>>>(deg, n, sbt);
        scan_tiny<<<1, 64, 0, stream>>>(sbt, nb, sbo);
        scan_final<<<nb, 1024, 0, stream>>>(deg, n, sbo, nb, off);
    };
    hist_int<<<2048, 256, 0, stream>>>(mol_dst, EM, mdeg);
    scan(mdeg, moff, NM);
    bin_by<<<2048, 256, 0, stream>>>(mol_dst, EM, moff, mcur, mbins);
    dinv_from_deg<<<512, 256, 0, stream>>>(mdeg, dinv, NM);
    mol_enorm<<<1024, 256, 0, stream>>>(mol_src, mol_dst, dinv, EM, enM);
    flatten_mol<<<2048, 256, 0, stream>>>(mbins, mol_src, enM, EM, ebM);

    hist_int<<<2048, 256, 0, stream>>>(kg_dst, EK, kdeg);
    scan(kdeg, koff, NKG);
    bin_by<<<2048, 256, 0, stream>>>(kg_dst, EK, koff, kcur, kbins);
    kg_cnt<<<2048, 256, 0, stream>>>(kg_dst, kg_et, EK, NKG, cntK);
    kg_enorm<<<1024, 256, 0, stream>>>(kg_dst, kg_et, cntK, EK, NKG, enK);

    hist_int<<<512, 256, 0, stream>>>(mol_batch, NM, pdeg);
    scan(pdeg, poff, ND);
    bin_by<<<512, 256, 0, stream>>>(mol_batch, NM, poff, pcur, pbins);

    // ---- BN helpers ----
    auto bn_stats = [&](const float* X, int M, int N, int lgN) {
        colstats_part<<<64, 512, 0, stream>>>(X, M, N, lgN, 512 >> lgN, part1, part2);
        colstats_reduce<<<1, N, 0, stream>>>(part1, part2, 64, N, 1.0f / M,
                                             stats, stats + 512);
    };
    auto bn_stats_b16 = [&](const u16* X, int M, int ld, int c0) {
        colstats_part_b16<<<64, 512, 0, stream>>>(X, M, ld, c0, part1, part2);
        colstats_reduce<<<1, 64, 0, stream>>>(part1, part2, 64, 64, 1.0f / M,
                                              stats, stats + 512);
    };

    // ---------- fingerprint MLP branch (MFMA) ----------
    conv_dual_b16<<<2048, 256, 0, stream>>>(fp_data, Xfb, (long)ND * 1024, flag);
    gemm_mfma<float><<<dim3(64, 8, 1), 256, 0, stream>>>(
        Xfb, 1024, fp_w1b, 512, fp1, 512, ND, 512, 1024, 0, 0);
    bn_stats(fp1, ND, 512, 9);
    bn_apply_dual<<<2048, 256, 0, stream>>>(fp1, fp1b, (long)ND * 512, 511,
                                            stats, stats + 512);
    gemm_mfma<float><<<dim3(64, 4, 1), 256, 0, stream>>>(
        fp1b, 512, fp_w2b, 256, fpb, 256, ND, 256, 512, 0, 0);
    bn_stats(fpb, ND, 256, 8);
    bn_apply<<<2048, 256, 0, stream>>>(fpb, (long)ND * 256, 255, stats, stats + 512);

    // ---------- mol GCN layer 1: bf16-convert, aggregate-then-GEMM ----------
    // XB overlaps fp1 (dead: fp gemm2 consumed fp1b); Xagg overwrites fp1b (dead)
    conv_molx<<<2048, 256, 0, stream>>>((const float*)mol_x, XB, (long)NM * 16, flag);
    mol_agg_in<<<32768, 256, 0, stream>>>(mol_x, XB, flag, dinv, moff, ebM, NM, Xagg);
    gemm_mfma<u16><<<dim3(2048, 2, 1), 256, 0, stream>>>(
        Xagg, 64, gcn_w1b, 128, G1, 128, NM, 128, 64, 0, 0);   // G1 overwrites XB (dead)
    for (int c0 = 0; c0 < 128; c0 += 64) {
        bn_stats_b16(G1, NM, 128, c0);
        bn_apply_b16<<<8192, 256, 0, stream>>>(G1, (long)NM * 64, 128, c0,
                                               stats, stats + 512);
    }

    // ---------- mol GCN layer 2: aggregate-then-GEMM + BN + pool ------------
    mol_agg128<<<32768, 256, 0, stream>>>(G1, dinv, moff, ebM, NM, G1A);
    // ebM (gout) is dead past this point; pool_b16 below may overwrite gout
    for (int c0 = 0; c0 < 256; c0 += 64) {
        gemm_mfma<u16><<<dim3(2048, 1, 1), 256, 0, stream>>>(
            G1A, 128, gcn_w2b + c0, 256, HB, 64, NM, 64, 128, 0, 0);
        bn_stats_b16(HB, NM, 64, 0);
        pool_b16<<<1024, 256, 0, stream>>>(HB, poff, pbins, ND,
                                           stats, stats + 512, gout, c0);
    }

    // ---------- attention fusion ----------
    attention_fuse<<<ND, 128, 0, stream>>>(gout, fpb, att_w1c, att_b1c, att_w2c,
                                           xkg, out_beta);
    // fpb is dead now; build flattened KG edge table in its place
    flatten_kg<<<2048, 256, 0, stream>>>(kbins, kg_src, kg_et, enK, EK, NKG, ebK);
    conv_in<<<512, 256, 0, stream>>>(d_in[17], xkg + (long)ND * 256,
                                     (long)NGENE * 256, flag);
    conv_f32_b16<<<1024, 256, 0, stream>>>(xkg, xb, (long)NKG * 256);

    // ---------- RGCN layer 1 (256 -> 256) ----------
    gemm_mfma<float><<<dim3(divup(NKG, 64), 4, 1), 256, 0, stream>>>(
        xb, 256, rg_root1b, 256, x2, 256, NKG, 256, 256, 0, 0);
    for (int c0 = 0; c0 < 256; c0 += 128) {
        gemm_mfma<u16><<<dim3(divup(NKG, 64), 2, 8), 256, 0, stream>>>(
            xb, 256, rg_w1b + c0, 256, HR, 128, NKG, 128, 256,
            (long)256 * 256, (long)NKG * 128);
        rgcn_agg128<<<2378, 256, 0, stream>>>(HR, koff, ebK, NKG, x2, 256, c0);
    }
    bn_stats(x2, NKG, 256, 8);
    bn_apply_dual<<<2048, 256, 0, stream>>>(x2, x2b, (long)NKG * 256, 255,
                                            stats, stats + 512);

    // ---------- RGCN layer 2 (256 -> 128) ----------
    gemm_mfma<float><<<dim3(divup(NKG, 64), 2, 1), 256, 0, stream>>>(
        x2b, 256, rg_root2b, 128, x3, 128, NKG, 128, 256, 0, 0);
    gemm_mfma<u16><<<dim3(divup(NKG, 64), 2, 8), 256, 0, stream>>>(
        x2b, 256, rg_w2b, 128, HR, 128, NKG, 128, 256,
        (long)256 * 128, (long)NKG * 128);
    rgcn_agg128<<<2378, 256, 0, stream>>>(HR, koff, ebK, NKG, x3, 128, 0);
    bn_stats(x3, NKG, 128, 7);
    bn_apply<<<2048, 256, 0, stream>>>(x3, (long)NKG * 128, 127, stats, stats + 512);

    // ---------- classifier head ----------
    gemm64<<<dim3(divup(NKG, 64), 1, 1), 256, 0, stream>>>(
        x3, 128, lin1_wc, 64, x4, 64, NKG, 64, 128);
    bn_stats(x4, NKG, 64, 6);
    logits_out_bn<<<divup(NKG, 256), 256, 0, stream>>>(x4, stats, stats + 512,
                                                       lin2_wc, lin2_bc, out_ls, NKG);
}

// Round 2
// 1406.705 us; speedup vs baseline: 1.3169x; 1.2270x over previous
//
#include <hip/hip_runtime.h>
#include <hip/hip_bf16.h>
#include <cstdint>

typedef __hip_bfloat16 bf16;
typedef unsigned short u16;
typedef unsigned int u32;
typedef __attribute__((ext_vector_type(8))) short short8;
typedef __attribute__((ext_vector_type(4))) float f32x4;

__device__ __forceinline__ float tofloat(float x){ return x; }
__device__ __forceinline__ float tofloat(bf16 x){ return __bfloat162float(x); }
__device__ __forceinline__ float b2f(u16 a){ return __uint_as_float(((unsigned)a) << 16); }
__device__ __forceinline__ u16 f2b(float f){           // round-to-nearest-even
    unsigned u = __float_as_uint(f);
    return (u16)((u + 0x7FFFu + ((u >> 16) & 1u)) >> 16);
}
__device__ __forceinline__ void storec(float* p, float v){ *p = v; }
__device__ __forceinline__ void storec(u16* p, float v){ *p = f2b(v); }

static inline int divup(long a, long b){ return (int)((a + b - 1) / b); }

#define NBLK_STATS 256

// ---------------- input dtype detection -------------------------------------
__global__ void zero_int(int* p){ *p = 0; }

__global__ void detect_f32(const u16* __restrict__ h, long n, int* flag)
{
    long i = (long)blockIdx.x * blockDim.x + threadIdx.x;
    long st = (long)gridDim.x * blockDim.x;
    int c = 0;
    for (; i < n; i += st)
        if (((h[i] >> 7) & 0xFF) == 0xFF) c++;
    if (c) atomicAdd(flag, c);
}

// convert all weights: fp32 pool + bf16 pool in one launch
struct ConvTab { const void* src[14]; float* dst[14]; u16* dstB[14]; int n[14]; };

__global__ void conv_all(ConvTab t, const int* __restrict__ flagp)
{
    bool f32 = (*flagp != 0);
    int seg = blockIdx.y;
    const void* s = t.src[seg];
    float* d = t.dst[seg];
    u16*   dB = t.dstB[seg];
    int n = t.n[seg];
    long i = (long)blockIdx.x * blockDim.x + threadIdx.x;
    long st = (long)gridDim.x * blockDim.x;
    for (; i < n; i += st) {
        float v = f32 ? ((const float*)s)[i] : tofloat(((const bf16*)s)[i]);
        d[i] = v; dB[i] = f2b(v);
    }
}

__global__ void conv_in(const void* __restrict__ src, float* __restrict__ dst,
                        long n, const int* __restrict__ flagp)
{
    bool f32 = (*flagp != 0);
    long i = (long)blockIdx.x * blockDim.x + threadIdx.x;
    long st = (long)gridDim.x * blockDim.x;
    for (; i < n; i += st)
        dst[i] = f32 ? ((const float*)src)[i] : tofloat(((const bf16*)src)[i]);
}

__global__ void conv_dual_b16(const void* __restrict__ src, u16* __restrict__ dst,
                              long n, const int* __restrict__ flagp)
{
    bool f32 = (*flagp != 0);
    long i = (long)blockIdx.x * blockDim.x + threadIdx.x;
    long st = (long)gridDim.x * blockDim.x;
    for (; i < n; i += st)
        dst[i] = f32 ? f2b(((const float*)src)[i]) : ((const u16*)src)[i];
}

__global__ void conv_f32_b16(const float* __restrict__ src, u16* __restrict__ dst, long n)
{
    long i = (long)blockIdx.x * blockDim.x + threadIdx.x;
    long st = (long)gridDim.x * blockDim.x;
    for (; i < n; i += st) dst[i] = f2b(src[i]);
}

// convert mol_x fp32 -> bf16 copy (only when input is fp32); vectorized x4
__global__ void conv_molx(const float* __restrict__ src, u16* __restrict__ dst,
                          long n4, const int* __restrict__ flagp)
{
    if (*flagp == 0) return;   // input already bf16; agg reads original
    long i = (long)blockIdx.x * blockDim.x + threadIdx.x;
    long st = (long)gridDim.x * blockDim.x;
    for (; i < n4; i += st) {
        float4 v = ((const float4*)src)[i];
        ushort4 o;
        o.x = f2b(v.x); o.y = f2b(v.y); o.z = f2b(v.z); o.w = f2b(v.w);
        ((ushort4*)dst)[i] = o;
    }
}

// ---------------- CSR edge flattening ---------------------------------------
__global__ void flatten_mol(const int* __restrict__ bins, const int* __restrict__ src,
                            const float* __restrict__ en, long E, int2* __restrict__ out)
{
    long i = (long)blockIdx.x * blockDim.x + threadIdx.x;
    long st = (long)gridDim.x * blockDim.x;
    for (; i < E; i += st) {
        int e = bins[i];
        out[i] = make_int2(src[e], __float_as_int(en[e]));
    }
}

__global__ void flatten_kg(const int* __restrict__ bins, const int* __restrict__ src,
                           const int* __restrict__ et, const float* __restrict__ en,
                           long E, int NKG, int2* __restrict__ out)
{
    long i = (long)blockIdx.x * blockDim.x + threadIdx.x;
    long st = (long)gridDim.x * blockDim.x;
    for (; i < E; i += st) {
        int e = bins[i];
        out[i] = make_int2(et[e] * NKG + src[e], __float_as_int(en[e]));
    }
}

// ---------------- MFMA GEMM: C[M,N] = A[M,K] @ B[K,N], bf16 in, fp32 acc ----
template<typename TC>
__global__ __launch_bounds__(256)
void gemm_mfma(const u16* __restrict__ A, int lda,
               const u16* __restrict__ B, int ldb,
               TC* __restrict__ C, int ldc,
               int M, int N, int K, long sB, long sC)
{
    __shared__ __align__(16) u16 As[64][40];   // [m][k], stride 80 B
    __shared__ __align__(16) u16 Bs[64][40];   // [n][k] (transposed)
    const u16* Bp = B + (long)blockIdx.z * sB;
    TC*        Cp = C + (long)blockIdx.z * sC;
    const int tid = threadIdx.x;
    const int lane = tid & 63, wave = tid >> 6;
    const int l15 = lane & 15, quad = lane >> 4;
    const int wm = (wave & 1) * 32, wn = (wave >> 1) * 32;
    const int row0 = blockIdx.x * 64, col0 = blockIdx.y * 64;
    const int arow = tid >> 2, ak = (tid & 3) * 8;
    const int bk = tid >> 3,  bn = (tid & 7) * 8;

    f32x4 acc[2][2];
#pragma unroll
    for (int i = 0; i < 2; i++)
#pragma unroll
        for (int j = 0; j < 2; j++)
#pragma unroll
            for (int r = 0; r < 4; r++) acc[i][j][r] = 0.f;

    for (int k0 = 0; k0 < K; k0 += 32) {
        {   // stage A: 64 rows x 32 k
            int r = row0 + arow;
            ushort4 v0 = {0,0,0,0}, v1 = {0,0,0,0};
            if (r < M) {
                const u16* p = A + (long)r * lda + k0 + ak;
                v0 = *(const ushort4*)p;
                v1 = *(const ushort4*)(p + 4);
            }
            *(ushort4*)&As[arow][ak]     = v0;
            *(ushort4*)&As[arow][ak + 4] = v1;
        }
        {   // stage B transposed: Bs[n][k]
            const u16* p = Bp + (long)(k0 + bk) * ldb + col0 + bn;
            ushort4 v0 = *(const ushort4*)p;
            ushort4 v1 = *(const ushort4*)(p + 4);
            Bs[bn + 0][bk] = v0.x; Bs[bn + 1][bk] = v0.y;
            Bs[bn + 2][bk] = v0.z; Bs[bn + 3][bk] = v0.w;
            Bs[bn + 4][bk] = v1.x; Bs[bn + 5][bk] = v1.y;
            Bs[bn + 6][bk] = v1.z; Bs[bn + 7][bk] = v1.w;
        }
        __syncthreads();
        short8 a0 = *(const short8*)&As[wm + l15][quad * 8];
        short8 a1 = *(const short8*)&As[wm + 16 + l15][quad * 8];
        short8 b0 = *(const short8*)&Bs[wn + l15][quad * 8];
        short8 b1 = *(const short8*)&Bs[wn + 16 + l15][quad * 8];
        acc[0][0] = __builtin_amdgcn_mfma_f32_16x16x32_bf16(a0, b0, acc[0][0], 0, 0, 0);
        acc[0][1] = __builtin_amdgcn_mfma_f32_16x16x32_bf16(a0, b1, acc[0][1], 0, 0, 0);
        acc[1][0] = __builtin_amdgcn_mfma_f32_16x16x32_bf16(a1, b0, acc[1][0], 0, 0, 0);
        acc[1][1] = __builtin_amdgcn_mfma_f32_16x16x32_bf16(a1, b1, acc[1][1], 0, 0, 0);
        __syncthreads();
    }
#pragma unroll
    for (int i = 0; i < 2; i++)
#pragma unroll
        for (int j = 0; j < 2; j++)
#pragma unroll
            for (int r = 0; r < 4; r++) {
                int row = row0 + wm + i * 16 + quad * 4 + r;
                int col = col0 + wn + j * 16 + l15;
                if (row < M) storec(&Cp[(long)row * ldc + col], acc[i][j][r]);
            }
}

// ---------------- vector GEMM (fp32, small) ---------------------------------
__global__ __launch_bounds__(256)
void gemm64(const float* __restrict__ A, int lda,
            const float* __restrict__ B, int ldb,
            float* __restrict__ C, int ldc,
            int M, int N, int K)
{
    __shared__ float As[16][68];
    __shared__ float Bs[16][68];
    const int tid = threadIdx.x;
    const int row0 = blockIdx.x * 64, col0 = blockIdx.y * 64;
    float acc[4][4];
#pragma unroll
    for (int i = 0; i < 4; i++)
#pragma unroll
        for (int j = 0; j < 4; j++) acc[i][j] = 0.f;
    const int ar = tid >> 2, ak = (tid & 3) * 4;
    const int bk = tid >> 4, bc = (tid & 15) * 4;
    const int ty4 = (tid >> 4) * 4, tx4 = (tid & 15) * 4;
    for (int k0 = 0; k0 < K; k0 += 16) {
        {
            int row = row0 + ar;
            float4 v = make_float4(0.f, 0.f, 0.f, 0.f);
            if (row < M) v = *(const float4*)(A + (long)row * lda + k0 + ak);
            As[ak + 0][ar] = v.x; As[ak + 1][ar] = v.y;
            As[ak + 2][ar] = v.z; As[ak + 3][ar] = v.w;
        }
        {
            int c = col0 + bc;
            float4 v = make_float4(0.f, 0.f, 0.f, 0.f);
            if (c < N) v = *(const float4*)(B + (long)(k0 + bk) * ldb + c);
            *(float4*)&Bs[bk][bc] = v;
        }
        __syncthreads();
#pragma unroll
        for (int k = 0; k < 16; k++) {
            float4 a = *(const float4*)&As[k][ty4];
            float4 b = *(const float4*)&Bs[k][tx4];
            acc[0][0] += a.x * b.x; acc[0][1] += a.x * b.y; acc[0][2] += a.x * b.z; acc[0][3] += a.x * b.w;
            acc[1][0] += a.y * b.x; acc[1][1] += a.y * b.y; acc[1][2] += a.y * b.z; acc[1][3] += a.y * b.w;
            acc[2][0] += a.z * b.x; acc[2][1] += a.z * b.y; acc[2][2] += a.z * b.z; acc[2][3] += a.z * b.w;
            acc[3][0] += a.w * b.x; acc[3][1] += a.w * b.y; acc[3][2] += a.w * b.z; acc[3][3] += a.w * b.w;
        }
        __syncthreads();
    }
    int c = col0 + tx4;
#pragma unroll
    for (int i = 0; i < 4; i++) {
        int r = row0 + ty4 + i;
        if (r < M && c < N)
            *(float4*)&C[(long)r * ldc + c] =
                make_float4(acc[i][0], acc[i][1], acc[i][2], acc[i][3]);
    }
}

// ---------------- utility / CSR build ---------------------------------------
__global__ void filli(int* p, long n, int v)
{
    long i = (long)blockIdx.x * blockDim.x + threadIdx.x;
    long st = (long)gridDim.x * blockDim.x;
    for (; i < n; i += st) p[i] = v;
}

__global__ void hist_int(const int* __restrict__ key, long n, int* __restrict__ h)
{
    long i = (long)blockIdx.x * blockDim.x + threadIdx.x;
    long st = (long)gridDim.x * blockDim.x;
    for (; i < n; i += st) atomicAdd(&h[key[i]], 1);
}

__global__ __launch_bounds__(1024)
void scan_bsum(const int* __restrict__ in, int n, int* __restrict__ btot)
{
    __shared__ int sh[1024];
    int tid = threadIdx.x;
    int i0 = blockIdx.x * 4096 + tid * 4;
    int s = 0;
#pragma unroll
    for (int t = 0; t < 4; t++) { int idx = i0 + t; s += (idx < n) ? in[idx] : 0; }
    sh[tid] = s;
    __syncthreads();
    for (int off = 512; off > 0; off >>= 1) {
        if (tid < off) sh[tid] += sh[tid + off];
        __syncthreads();
    }
    if (tid == 0) btot[blockIdx.x] = sh[0];
}

__global__ void scan_tiny(const int* __restrict__ btot, int nb, int* __restrict__ boff)
{
    if (threadIdx.x == 0) {
        int c = 0;
        for (int b = 0; b < nb; b++) { boff[b] = c; c += btot[b]; }
        boff[nb] = c;
    }
}

__global__ __launch_bounds__(1024)
void scan_final(const int* __restrict__ in, int n, const int* __restrict__ boff,
                int nb, int* __restrict__ out)
{
    __shared__ int buf[1024];
    int tid = threadIdx.x;
    int i0 = blockIdx.x * 4096 + tid * 4;
    int v[4]; int s = 0;
#pragma unroll
    for (int t = 0; t < 4; t++) {
        int idx = i0 + t;
        v[t] = (idx < n) ? in[idx] : 0;
        s += v[t];
    }
    buf[tid] = s;
    __syncthreads();
    for (int off = 1; off < 1024; off <<= 1) {
        int t = (tid >= off) ? buf[tid - off] : 0;
        __syncthreads();
        buf[tid] += t;
        __syncthreads();
    }
    int excl = buf[tid] - s + boff[blockIdx.x];
#pragma unroll
    for (int t = 0; t < 4; t++) {
        int idx = i0 + t;
        if (idx < n) out[idx] = excl;
        excl += v[t];
    }
    if (blockIdx.x == 0 && tid == 0) out[n] = boff[nb];
}

__global__ void bin_by(const int* __restrict__ key, long n,
                       const int* __restrict__ off, int* __restrict__ cursor,
                       int* __restrict__ bins)
{
    long i = (long)blockIdx.x * blockDim.x + threadIdx.x;
    long st = (long)gridDim.x * blockDim.x;
    for (; i < n; i += st) {
        int k = key[i];
        int pos = off[k] + atomicAdd(&cursor[k], 1);
        bins[pos] = (int)i;
    }
}

__global__ void dinv_from_deg(const int* __restrict__ deg, float* __restrict__ dinv, long n)
{
    long i = (long)blockIdx.x * blockDim.x + threadIdx.x;
    long st = (long)gridDim.x * blockDim.x;
    for (; i < n; i += st) dinv[i] = rsqrtf((float)(deg[i] + 1));
}

__global__ void kg_cnt(const int* __restrict__ dst, const int* __restrict__ et,
                       long E, int NKG, float* cnt)
{
    long i = (long)blockIdx.x * blockDim.x + threadIdx.x;
    long st = (long)gridDim.x * blockDim.x;
    for (; i < E; i += st) atomicAdd(&cnt[(long)et[i] * NKG + dst[i]], 1.0f);
}

__global__ void kg_enorm(const int* __restrict__ dst, const int* __restrict__ et,
                         const float* __restrict__ cnt, long E, int NKG,
                         float* __restrict__ en)
{
    long i = (long)blockIdx.x * blockDim.x + threadIdx.x;
    long st = (long)gridDim.x * blockDim.x;
    for (; i < E; i += st)
        en[i] = 1.0f / fmaxf(cnt[(long)et[i] * NKG + dst[i]], 1.0f);
}

__global__ void mol_enorm(const int* __restrict__ src, const int* __restrict__ dst,
                          const float* __restrict__ dinv, long E, float* __restrict__ en)
{
    long i = (long)blockIdx.x * blockDim.x + threadIdx.x;
    long st = (long)gridDim.x * blockDim.x;
    for (; i < E; i += st) en[i] = dinv[src[i]] * dinv[dst[i]];
}

// ---------------- batch-norm stats (v2: vectorized, NBLK_STATS blocks) ------
// bf16 matrix [M, ld], NC cols (64 or 128) at c0 -> partials p1,p2 [NBLK][NC]
__global__ __launch_bounds__(256)
void colstats_b16_v2(const u16* __restrict__ X, int M, int ld, int c0, int NC,
                     float* __restrict__ p1, float* __restrict__ p2)
{
    __shared__ float sh1[1024], sh2[1024];
    int tid = threadIdx.x;
    int ncg = NC >> 2;                 // col groups of 4
    int cg  = tid & (ncg - 1);
    int rg  = tid / ncg;
    int nrg = 256 / ncg;
    float s0=0,s1=0,s2=0,s3=0, q0=0,q1=0,q2=0,q3=0;
    const u16* base = X + c0 + 4 * cg;
    for (long row = (long)blockIdx.x * nrg + rg; row < M; row += (long)gridDim.x * nrg) {
        ushort4 v = *(const ushort4*)(base + row * (long)ld);
        float f0 = b2f(v.x), f1 = b2f(v.y), f2 = b2f(v.z), f3 = b2f(v.w);
        s0 += f0; q0 += f0 * f0; s1 += f1; q1 += f1 * f1;
        s2 += f2; q2 += f2 * f2; s3 += f3; q3 += f3 * f3;
    }
    float4* S1 = (float4*)sh1; float4* S2 = (float4*)sh2;
    S1[tid] = make_float4(s0, s1, s2, s3);
    S2[tid] = make_float4(q0, q1, q2, q3);
    __syncthreads();
    for (int off = nrg >> 1; off > 0; off >>= 1) {
        if (rg < off) {
            float4 a = S1[tid], b = S1[tid + off * ncg];
            S1[tid] = make_float4(a.x + b.x, a.y + b.y, a.z + b.z, a.w + b.w);
            float4 c = S2[tid], d = S2[tid + off * ncg];
            S2[tid] = make_float4(c.x + d.x, c.y + d.y, c.z + d.z, c.w + d.w);
        }
        __syncthreads();
    }
    if (rg == 0) {
        *(float4*)&p1[(long)blockIdx.x * NC + 4 * cg] = S1[tid];
        *(float4*)&p2[(long)blockIdx.x * NC + 4 * cg] = S2[tid];
    }
}

// fp32 matrix [M, N] (N in {64,128,256,512}) -> partials p1,p2 [NBLK][N]
__global__ __launch_bounds__(256)
void colstats_f32_v2(const float* __restrict__ X, int M, int N,
                     float* __restrict__ p1, float* __restrict__ p2)
{
    __shared__ float sh1[1024], sh2[1024];
    int tid = threadIdx.x;
    int ncg = N >> 2;
    int cg  = tid & (ncg - 1);
    int rg  = tid / ncg;
    int nrg = 256 / ncg;
    float s0=0,s1=0,s2=0,s3=0, q0=0,q1=0,q2=0,q3=0;
    const float* base = X + 4 * cg;
    for (long row = (long)blockIdx.x * nrg + rg; row < M; row += (long)gridDim.x * nrg) {
        float4 v = *(const float4*)(base + row * (long)N);
        s0 += v.x; q0 += v.x * v.x; s1 += v.y; q1 += v.y * v.y;
        s2 += v.z; q2 += v.z * v.z; s3 += v.w; q3 += v.w * v.w;
    }
    float4* S1 = (float4*)sh1; float4* S2 = (float4*)sh2;
    S1[tid] = make_float4(s0, s1, s2, s3);
    S2[tid] = make_float4(q0, q1, q2, q3);
    __syncthreads();
    for (int off = nrg >> 1; off > 0; off >>= 1) {
        if (rg < off) {
            float4 a = S1[tid], b = S1[tid + off * ncg];
            S1[tid] = make_float4(a.x + b.x, a.y + b.y, a.z + b.z, a.w + b.w);
            float4 c = S2[tid], d = S2[tid + off * ncg];
            S2[tid] = make_float4(c.x + d.x, c.y + d.y, c.z + d.z, c.w + d.w);
        }
        __syncthreads();
    }
    if (rg == 0) {
        *(float4*)&p1[(long)blockIdx.x * N + 4 * cg] = S1[tid];
        *(float4*)&p2[(long)blockIdx.x * N + 4 * cg] = S2[tid];
    }
}

// parallel reduce of partials: grid = N/64 blocks x 256 thr (4 segments)
__global__ void colstats_reduce_v2(const float* __restrict__ p1, const float* __restrict__ p2,
                                   int nblk, int N, float invM,
                                   float* __restrict__ s1o, float* __restrict__ s2o)
{
    __shared__ float sh1[256], sh2[256];
    int tid = threadIdx.x;
    int col = blockIdx.x * 64 + (tid & 63);
    int seg = tid >> 6;
    float a = 0.f, c = 0.f;
    for (int b = seg; b < nblk; b += 4) {
        a += p1[(long)b * N + col];
        c += p2[(long)b * N + col];
    }
    sh1[tid] = a; sh2[tid] = c;
    __syncthreads();
    if (seg == 0) {
        a = sh1[tid] + sh1[tid + 64] + sh1[tid + 128] + sh1[tid + 192];
        c = sh2[tid] + sh2[tid + 64] + sh2[tid + 128] + sh2[tid + 192];
        float mean = a * invM;
        float var  = fmaxf(c * invM - mean * mean, 0.f);
        s1o[col] = mean;
        s2o[col] = rsqrtf(var + 1e-5f);
    }
}

__global__ void bn_apply(float* X, long total, int mask,
                         const float* __restrict__ s1, const float* __restrict__ s2)
{
    long i = (long)blockIdx.x * blockDim.x + threadIdx.x;
    long st = (long)gridDim.x * blockDim.x;
    for (; i < total; i += st) {
        int j = (int)(i & mask);
        X[i] = fmaxf((X[i] - s1[j]) * s2[j], 0.f);
    }
}

// BN+ReLU, fp32 in place AND bf16 copy
__global__ void bn_apply_dual(float* __restrict__ X, u16* __restrict__ Xb, long total,
                              int mask, const float* __restrict__ s1,
                              const float* __restrict__ s2)
{
    long i = (long)blockIdx.x * blockDim.x + threadIdx.x;
    long st = (long)gridDim.x * blockDim.x;
    for (; i < total; i += st) {
        int j = (int)(i & mask);
        float y = fmaxf((X[i] - s1[j]) * s2[j], 0.f);
        X[i] = y;
        Xb[i] = f2b(y);
    }
}

// BN+ReLU in place on bf16 contiguous [M, NC]; u32 words (2 cols each)
// n2 = M*NC/2 words; maskHalf = NC/2 - 1
__global__ void bn_apply_b16_v2(u32* __restrict__ X, long n2, int maskHalf,
                                const float* __restrict__ s1, const float* __restrict__ s2)
{
    long i = (long)blockIdx.x * blockDim.x + threadIdx.x;
    long st = (long)gridDim.x * blockDim.x;
    for (; i < n2; i += st) {
        u32 v = X[i];
        int f = (int)(i & maskHalf) * 2;
        float y0 = fmaxf((b2f((u16)(v & 0xFFFF)) - s1[f])     * s2[f],     0.f);
        float y1 = fmaxf((b2f((u16)(v >> 16))    - s1[f + 1]) * s2[f + 1], 0.f);
        X[i] = (u32)f2b(y0) | ((u32)f2b(y1) << 16);
    }
}

// ---------------- CSR aggregation (no atomics) ------------------------------
__global__ __launch_bounds__(256)
void mol_agg_in(const void* __restrict__ Xraw, const u16* __restrict__ Xcvt,
                const int* __restrict__ flagp, const float* __restrict__ dinv,
                const int* __restrict__ off, const int2* __restrict__ eb,
                int NM, u16* __restrict__ out)
{
    const u16* X = (*flagp != 0) ? Xcvt : (const u16*)Xraw;
    int wid  = (int)(((long)blockIdx.x * 256 + threadIdx.x) >> 6);
    int lane = threadIdx.x & 63;
    if (wid >= NM) return;
    float dv = dinv[wid];
    float acc = b2f(X[(long)wid * 64 + lane]) * dv * dv;
    int j = off[wid], j1 = off[wid + 1];
    for (; j + 1 < j1; j += 2) {
        int2 e0 = eb[j], e1 = eb[j + 1];
        float v0 = b2f(X[(long)e0.x * 64 + lane]);
        float v1 = b2f(X[(long)e1.x * 64 + lane]);
        acc += v0 * __int_as_float(e0.y) + v1 * __int_as_float(e1.y);
    }
    if (j < j1) {
        int2 e = eb[j];
        acc += b2f(X[(long)e.x * 64 + lane]) * __int_as_float(e.y);
    }
    out[(long)wid * 64 + lane] = f2b(acc);
}

__global__ __launch_bounds__(256)
void mol_agg128(const u16* __restrict__ G, const float* __restrict__ dinv,
                const int* __restrict__ off, const int2* __restrict__ eb,
                int NM, u16* __restrict__ out)
{
    int wid  = (int)(((long)blockIdx.x * 256 + threadIdx.x) >> 6);
    int lane = threadIdx.x & 63;
    if (wid >= NM) return;
    float dv = dinv[wid], dv2 = dv * dv;
    u32 u = *(const u32*)(G + (long)wid * 128 + 2 * lane);
    float a0 = b2f((u16)(u & 0xFFFF)) * dv2;
    float a1 = b2f((u16)(u >> 16)) * dv2;
    int j = off[wid], j1 = off[wid + 1];
    for (; j + 1 < j1; j += 2) {
        int2 e0 = eb[j], e1 = eb[j + 1];
        u32 v0 = *(const u32*)(G + (long)e0.x * 128 + 2 * lane);
        u32 v1 = *(const u32*)(G + (long)e1.x * 128 + 2 * lane);
        float n0 = __int_as_float(e0.y), n1 = __int_as_float(e1.y);
        a0 += b2f((u16)(v0 & 0xFFFF)) * n0 + b2f((u16)(v1 & 0xFFFF)) * n1;
        a1 += b2f((u16)(v0 >> 16)) * n0 + b2f((u16)(v1 >> 16)) * n1;
    }
    if (j < j1) {
        int2 e = eb[j];
        u32 v = *(const u32*)(G + (long)e.x * 128 + 2 * lane);
        float n = __int_as_float(e.y);
        a0 += b2f((u16)(v & 0xFFFF)) * n;
        a1 += b2f((u16)(v >> 16)) * n;
    }
    u32 o = (u32)f2b(a0) | ((u32)f2b(a1) << 16);
    *(u32*)(out + (long)wid * 128 + 2 * lane) = o;
}

__global__ __launch_bounds__(256)
void rgcn_agg128(const u16* __restrict__ hr, const int* __restrict__ off,
                 const int2* __restrict__ eb,
                 int NKG, float* __restrict__ out, int ldout, int c0)
{
    int wid  = (int)(((long)blockIdx.x * 256 + threadIdx.x) >> 6);
    int lane = threadIdx.x & 63;
    if (wid >= NKG) return;
    float a0 = 0.f, a1 = 0.f;
    int j = off[wid], j1 = off[wid + 1];
    for (; j + 1 < j1; j += 2) {
        int2 e0 = eb[j], e1 = eb[j + 1];
        u32 u0 = *(const u32*)(hr + (long)e0.x * 128 + 2 * lane);
        u32 u1 = *(const u32*)(hr + (long)e1.x * 128 + 2 * lane);
        float n0 = __int_as_float(e0.y), n1 = __int_as_float(e1.y);
        a0 += b2f((u16)(u0 & 0xFFFF)) * n0 + b2f((u16)(u1 & 0xFFFF)) * n1;
        a1 += b2f((u16)(u0 >> 16)) * n0 + b2f((u16)(u1 >> 16)) * n1;
    }
    if (j < j1) {
        int2 e = eb[j];
        u32 u0 = *(const u32*)(hr + (long)e.x * 128 + 2 * lane);
        float n0 = __int_as_float(e.y);
        a0 += b2f((u16)(u0 & 0xFFFF)) * n0;
        a1 += b2f((u16)(u0 >> 16)) * n0;
    }
    float2* o = (float2*)(out + (long)wid * ldout + c0 + 2 * lane);
    float2 v = *o; v.x += a0; v.y += a1; *o = v;
}

// mean-pool bf16 chunk [NM,64] with fused BN+ReLU
__global__ __launch_bounds__(256)
void pool_b16(const u16* __restrict__ g, const int* __restrict__ off,
              const int* __restrict__ bins, int ND,
              const float* __restrict__ s1, const float* __restrict__ s2,
              float* __restrict__ gout, int c0)
{
    int wid  = (int)(((long)blockIdx.x * 256 + threadIdx.x) >> 6);
    int lane = threadIdx.x & 63;
    if (wid >= ND) return;
    float m = s1[lane], r = s2[lane];
    int j0 = off[wid], j1 = off[wid + 1];
    float acc = 0.f;
    for (int j = j0; j < j1; j++)
        acc += fmaxf((b2f(g[(long)bins[j] * 64 + lane]) - m) * r, 0.f);
    gout[(long)wid * 256 + c0 + lane] = acc / fmaxf((float)(j1 - j0), 1.0f);
}

// ---------------- attention fusion ------------------------------------------
__global__ void attention_fuse(const float* __restrict__ go, const float* __restrict__ fpv,
                               const float* __restrict__ W1, const float* __restrict__ B1,
                               const float* __restrict__ W2,
                               float* __restrict__ emb, float* __restrict__ beta_out)
{
    int d = blockIdx.x;
    int t = threadIdx.x;
    __shared__ float z[2][256];
    __shared__ float red[128];
    for (int c = t; c < 256; c += 128) {
        z[0][c] = go[(long)d * 256 + c];
        z[1][c] = fpv[(long)d * 256 + c];
    }
    __syncthreads();
    float s[2];
    for (int v = 0; v < 2; v++) {
        float acc = B1[t];
        for (int k = 0; k < 256; k++) acc += z[v][k] * W1[k * 128 + t];
        red[t] = tanhf(acc) * W2[t];
        __syncthreads();
        for (int off = 64; off > 0; off >>= 1) {
            if (t < off) red[t] += red[t + off];
            __syncthreads();
        }
        s[v] = red[0];
        __syncthreads();
    }
    float m = fmaxf(s[0], s[1]);
    float e0 = expf(s[0] - m), e1 = expf(s[1] - m);
    float inv = 1.0f / (e0 + e1);
    float b0 = e0 * inv, b1 = e1 * inv;
    for (int c = t; c < 256; c += 128)
        emb[(long)d * 256 + c] = b0 * z[0][c] + b1 * z[1][c];
    if (t == 0) {
        beta_out[d * 2 + 0] = b0;
        beta_out[d * 2 + 1] = b1;
    }
}

// ---------------- final linear + log_softmax, fused BN on x4 ----------------
__global__ void logits_out_bn(const float* __restrict__ x4,
                              const float* __restrict__ s1, const float* __restrict__ s2,
                              const float* __restrict__ w, const float* __restrict__ b,
                              float* __restrict__ out, int NKG)
{
    int i = blockIdx.x * blockDim.x + threadIdx.x;
    if (i >= NKG) return;
    float a0 = b[0], a1 = b[1];
    for (int k = 0; k < 64; k++) {
        float v = fmaxf((x4[(long)i * 64 + k] - s1[k]) * s2[k], 0.f);
        a0 += v * w[k * 2 + 0];
        a1 += v * w[k * 2 + 1];
    }
    float m = fmaxf(a0, a1);
    float lse = m + logf(expf(a0 - m) + expf(a1 - m));
    out[i * 2 + 0] = a0 - lse;
    out[i * 2 + 1] = a1 - lse;
}

// ============================================================================
extern "C" void kernel_launch(void* const* d_in, const int* in_sizes, int n_in,
                              void* d_out, int out_size, void* d_ws, size_t ws_size,
                              hipStream_t stream)
{
    (void)in_sizes; (void)n_in; (void)out_size; (void)ws_size;
    const int ND = 4096, NM = 131072, NKG = 9510, NGENE = 5414;
    const long EM = 524288, EK = 524288;

    const void* fp_data = d_in[0];
    const void* mol_x   = d_in[1];
    const int*  mol_batch = (const int*)d_in[2];
    const int*  mol_ei  = (const int*)d_in[3];
    const int*  kg_ei   = (const int*)d_in[4];
    const int*  kg_et   = (const int*)d_in[5];

    const int* mol_src = mol_ei;
    const int* mol_dst = mol_ei + EM;
    const int* kg_src  = kg_ei;
    const int* kg_dst  = kg_ei + EK;

    float* out_ls   = (float*)d_out;          // [9510,2] fp32
    float* out_beta = (float*)d_out + 19020;  // [4096,2,1] fp32

    // ---- workspace carve ----
    char* wp = (char*)d_ws;
    auto carve = [&](size_t bytes) { char* p = wp; wp += (bytes + 255) & ~(size_t)255; return p; };
    float* stats = (float*)carve(4096);
    int*   flag  = (int*)carve(256);
    float* dinv  = (float*)carve((size_t)NM * 4);
    float* enM   = (float*)carve((size_t)EM * 4);
    float* enK   = (float*)carve((size_t)EK * 4);
    float* part1 = (float*)carve((size_t)NBLK_STATS * 512 * 4);   // 512 KB
    float* part2 = (float*)carve((size_t)NBLK_STATS * 512 * 4);
    int*   sbt   = (int*)carve(256);
    int*   sbo   = (int*)carve(256);
    float* Wpool = (float*)carve((size_t)1630000 * 4);     // fp32 weights
    u16*   WpoolB= (u16*)carve((size_t)1630000 * 2);       // bf16 weights
    float* fpb   = (float*)carve((size_t)ND * 256 * 4);
    float* gout  = (float*)carve((size_t)ND * 256 * 4);
    // zero-span
    char*  z0    = wp;
    float* cntK  = (float*)carve((size_t)8 * NKG * 4);
    int* mdeg = (int*)carve((size_t)NM * 4);
    int* mcur = (int*)carve((size_t)NM * 4);
    int* kdeg = (int*)carve((size_t)NKG * 4);
    int* kcur = (int*)carve((size_t)NKG * 4);
    int* pdeg = (int*)carve((size_t)ND * 4);
    int* pcur = (int*)carve((size_t)ND * 4);
    char*  z1    = wp;
    int* moff = (int*)carve((size_t)(NM + 1) * 4);
    int* mbins= (int*)carve((size_t)EM * 4);
    int* koff = (int*)carve((size_t)(NKG + 1) * 4);
    int* kbins= (int*)carve((size_t)EK * 4);
    int* poff = (int*)carve((size_t)(ND + 1) * 4);
    int* pbins= (int*)carve((size_t)NM * 4);
    char*  REG1  = carve((size_t)NM * 128 * 2);            // 33.6 MB
    char*  REG2  = carve((size_t)NM * 128 * 2);            // 33.6 MB
    u16*   HB    = (u16*)carve((size_t)NM * 64 * 2);       // 16.8 MB

    // phase views
    float* fp1 = (float*)REG1;                 // fp: [4096,512] f32
    u16*   XB  = (u16*)REG1;                   // mol pre: [NM,64] bf16 converted input
    u16*   G1  = (u16*)REG1;                   // mol: [NM,128] bf16
    float* xkg = (float*)REG1;                 // rgcn: x chain f32
    float* x2  = xkg + (size_t)NKG * 256;
    float* x3  = x2  + (size_t)NKG * 256;
    float* x4  = x3  + (size_t)NKG * 128;
    u16*   Xfb = (u16*)REG2;                   // fp: [4096,1024] bf16
    u16*   G1A = (u16*)REG2;                   // mol: [NM,128] bf16 aggregated
    u16*   HR  = (u16*)REG2;                   // rgcn: [8,NKG,128] bf16
    u16*   xb  = HR + (size_t)8 * NKG * 128;   // [NKG,256] bf16
    u16*   x2b = xb + (size_t)NKG * 256;       // [NKG,256] bf16
    u16*   fp1b = HB;                          // fp: [4096,512] bf16
    u16*   Xagg = HB;                          // mol L1: [NM,64] bf16
    // flattened CSR edge tables (aliased; lifetimes verified)
    int2* ebM = (int2*)gout;                   // EM*8 == ND*256*4 bytes exactly
    int2* ebK = (int2*)fpb;                    // EK*8 == ND*256*4 bytes exactly

    // ---- dtype detect + weight conversion (fp32 + bf16 pools) ----
    zero_int<<<1, 1, 0, stream>>>(flag);
    detect_f32<<<1024, 256, 0, stream>>>((const u16*)fp_data, (long)ND * 1024, flag);
    ConvTab tab;
    const int widx[14] = {6, 8, 10, 12, 14, 15, 16, 18, 19, 21, 22, 24, 26, 27};
    const int wn[14]   = {1024*512, 512*256, 64*128, 128*256, 256*128, 128, 128,
                          8*256*256, 256*256, 8*256*128, 256*128, 128*64, 64*2, 2};
    float* wf[14]; u16* wb[14];
    {
        size_t o = 0;
        for (int i = 0; i < 14; i++) {
            tab.src[i]  = d_in[widx[i]];
            tab.dst[i]  = Wpool + o;
            tab.dstB[i] = WpoolB + o;
            tab.n[i]    = wn[i];
            wf[i] = Wpool + o; wb[i] = WpoolB + o;
            o += (size_t)wn[i];
        }
    }
    conv_all<<<dim3(32, 14), 256, 0, stream>>>(tab, flag);
    u16 *fp_w1b = wb[0], *fp_w2b = wb[1], *gcn_w1b = wb[2], *gcn_w2b = wb[3];
    float *att_w1c = wf[4], *att_b1c = wf[5], *att_w2c = wf[6];
    u16 *rg_w1b = wb[7], *rg_root1b = wb[8], *rg_w2b = wb[9], *rg_root2b = wb[10];
    float *lin1_wc = wf[11], *lin2_wc = wf[12], *lin2_bc = wf[13];

    // ---- CSR builds ----
    filli<<<512, 256, 0, stream>>>((int*)z0, (long)(z1 - z0) / 4, 0);
    auto scan = [&](const int* deg, int* off, int n) {
        int nb = divup(n, 4096);
        scan_bsum<<<nb, 1024, 0, stream>>>(deg, n, sbt);
        scan_tiny<<<1, 64, 0, stream>>>(sbt, nb, sbo);
        scan_final<<<nb, 1024, 0, stream>>>(deg, n, sbo, nb, off);
    };
    hist_int<<<2048, 256, 0, stream>>>(mol_dst, EM, mdeg);
    scan(mdeg, moff, NM);
    bin_by<<<2048, 256, 0, stream>>>(mol_dst, EM, moff, mcur, mbins);
    dinv_from_deg<<<512, 256, 0, stream>>>(mdeg, dinv, NM);
    mol_enorm<<<1024, 256, 0, stream>>>(mol_src, mol_dst, dinv, EM, enM);
    flatten_mol<<<2048, 256, 0, stream>>>(mbins, mol_src, enM, EM, ebM);

    hist_int<<<2048, 256, 0, stream>>>(kg_dst, EK, kdeg);
    scan(kdeg, koff, NKG);
    bin_by<<<2048, 256, 0, stream>>>(kg_dst, EK, koff, kcur, kbins);
    kg_cnt<<<2048, 256, 0, stream>>>(kg_dst, kg_et, EK, NKG, cntK);
    kg_enorm<<<1024, 256, 0, stream>>>(kg_dst, kg_et, cntK, EK, NKG, enK);

    hist_int<<<512, 256, 0, stream>>>(mol_batch, NM, pdeg);
    scan(pdeg, poff, ND);
    bin_by<<<512, 256, 0, stream>>>(mol_batch, NM, poff, pcur, pbins);

    // ---- BN helpers (v2) ----
    auto bn_stats = [&](const float* X, int M, int N) {
        colstats_f32_v2<<<NBLK_STATS, 256, 0, stream>>>(X, M, N, part1, part2);
        colstats_reduce_v2<<<N / 64, 256, 0, stream>>>(part1, part2, NBLK_STATS, N,
                                                       1.0f / M, stats, stats + 512);
    };
    auto bn_stats_b16 = [&](const u16* X, int M, int ld, int c0, int NC) {
        colstats_b16_v2<<<NBLK_STATS, 256, 0, stream>>>(X, M, ld, c0, NC, part1, part2);
        colstats_reduce_v2<<<NC / 64, 256, 0, stream>>>(part1, part2, NBLK_STATS, NC,
                                                        1.0f / M, stats, stats + 512);
    };

    // ---------- fingerprint MLP branch (MFMA) ----------
    conv_dual_b16<<<2048, 256, 0, stream>>>(fp_data, Xfb, (long)ND * 1024, flag);
    gemm_mfma<float><<<dim3(64, 8, 1), 256, 0, stream>>>(
        Xfb, 1024, fp_w1b, 512, fp1, 512, ND, 512, 1024, 0, 0);
    bn_stats(fp1, ND, 512);
    bn_apply_dual<<<2048, 256, 0, stream>>>(fp1, fp1b, (long)ND * 512, 511,
                                            stats, stats + 512);
    gemm_mfma<float><<<dim3(64, 4, 1), 256, 0, stream>>>(
        fp1b, 512, fp_w2b, 256, fpb, 256, ND, 256, 512, 0, 0);
    bn_stats(fpb, ND, 256);
    bn_apply<<<2048, 256, 0, stream>>>(fpb, (long)ND * 256, 255, stats, stats + 512);

    // ---------- mol GCN layer 1: bf16-convert, aggregate-then-GEMM ----------
    conv_molx<<<2048, 256, 0, stream>>>((const float*)mol_x, XB, (long)NM * 16, flag);
    mol_agg_in<<<32768, 256, 0, stream>>>(mol_x, XB, flag, dinv, moff, ebM, NM, Xagg);
    gemm_mfma<u16><<<dim3(2048, 2, 1), 256, 0, stream>>>(
        Xagg, 64, gcn_w1b, 128, G1, 128, NM, 128, 64, 0, 0);   // G1 overwrites XB (dead)
    // joint 128-col BN (two independent 64-col BNs back-to-back in memory)
    bn_stats_b16(G1, NM, 128, 0, 128);
    bn_apply_b16_v2<<<8192, 256, 0, stream>>>((u32*)G1, (long)NM * 64, 63,
                                              stats, stats + 512);

    // ---------- mol GCN layer 2: aggregate-then-GEMM + BN + pool ------------
    mol_agg128<<<32768, 256, 0, stream>>>(G1, dinv, moff, ebM, NM, G1A);
    // ebM (gout) is dead past this point; pool_b16 below may overwrite gout
    for (int c0 = 0; c0 < 256; c0 += 64) {
        gemm_mfma<u16><<<dim3(2048, 1, 1), 256, 0, stream>>>(
            G1A, 128, gcn_w2b + c0, 256, HB, 64, NM, 64, 128, 0, 0);
        bn_stats_b16(HB, NM, 64, 0, 64);
        pool_b16<<<1024, 256, 0, stream>>>(HB, poff, pbins, ND,
                                           stats, stats + 512, gout, c0);
    }

    // ---------- attention fusion ----------
    attention_fuse<<<ND, 128, 0, stream>>>(gout, fpb, att_w1c, att_b1c, att_w2c,
                                           xkg, out_beta);
    // fpb is dead now; build flattened KG edge table in its place
    flatten_kg<<<2048, 256, 0, stream>>>(kbins, kg_src, kg_et, enK, EK, NKG, ebK);
    conv_in<<<512, 256, 0, stream>>>(d_in[17], xkg + (long)ND * 256,
                                     (long)NGENE * 256, flag);
    conv_f32_b16<<<1024, 256, 0, stream>>>(xkg, xb, (long)NKG * 256);

    // ---------- RGCN layer 1 (256 -> 256) ----------
    gemm_mfma<float><<<dim3(divup(NKG, 64), 4, 1), 256, 0, stream>>>(
        xb, 256, rg_root1b, 256, x2, 256, NKG, 256, 256, 0, 0);
    for (int c0 = 0; c0 < 256; c0 += 128) {
        gemm_mfma<u16><<<dim3(divup(NKG, 64), 2, 8), 256, 0, stream>>>(
            xb, 256, rg_w1b + c0, 256, HR, 128, NKG, 128, 256,
            (long)256 * 256, (long)NKG * 128);
        rgcn_agg128<<<2378, 256, 0, stream>>>(HR, koff, ebK, NKG, x2, 256, c0);
    }
    bn_stats(x2, NKG, 256);
    bn_apply_dual<<<2048, 256, 0, stream>>>(x2, x2b, (long)NKG * 256, 255,
                                            stats, stats + 512);

    // ---------- RGCN layer 2 (256 -> 128) ----------
    gemm_mfma<float><<<dim3(divup(NKG, 64), 2, 1), 256, 0, stream>>>(
        x2b, 256, rg_root2b, 128, x3, 128, NKG, 128, 256, 0, 0);
    gemm_mfma<u16><<<dim3(divup(NKG, 64), 2, 8), 256, 0, stream>>>(
        x2b, 256, rg_w2b, 128, HR, 128, NKG, 128, 256,
        (long)256 * 128, (long)NKG * 128);
    rgcn_agg128<<<2378, 256, 0, stream>>>(HR, koff, ebK, NKG, x3, 128, 0);
    bn_stats(x3, NKG, 128);
    bn_apply<<<2048, 256, 0, stream>>>(x3, (long)NKG * 128, 127, stats, stats + 512);

    // ---------- classifier head ----------
    gemm64<<<dim3(divup(NKG, 64), 1, 1), 256, 0, stream>>>(
        x3, 128, lin1_wc, 64, x4, 64, NKG, 64, 128);
    bn_stats(x4, NKG, 64);
    logits_out_bn<<<divup(NKG, 256), 256, 0, stream>>>(x4, stats, stats + 512,
                                                       lin2_wc, lin2_bc, out_ls, NKG);
}